// Round 10
// baseline (134.661 us; speedup 1.0000x reference)
//
#include <hip/hip_runtime.h>
#include <hip/hip_bf16.h>

typedef unsigned long long u64;
typedef unsigned int u32;

#define NB 64
#define NP 2048
#define NT 256
#define TK 8          // sorted top-K kept per row
#define RB 8          // rows resolved per greedy batch (RB*TK = 64 lanes)
#define NZ 4          // batch-dimension split of cost phase
#define BZ (NB / NZ)  // 16 batches per block
#define TT 8          // targets per block
#define EPSF 1e-7f

// ---------- phase 1: partial[z][t][p] = sum_{b in chunk z} iou ----------
__device__ inline void phase1(const float4* __restrict__ pred,
                              const float* __restrict__ tgt,
                              float* __restrict__ partial,
                              int bx, int by, int bz, int tid,
                              float* __restrict__ sAt /*[BZ*TT]*/) {
    const int t0 = by * TT;
    const int p = bx * 256 + tid;

    if (tid < BZ * TT) {
        int b = tid >> 3, tt = tid & 7;
        float4 tb = *(const float4*)&tgt[((bz * BZ + b) * NT + t0 + tt) * 4];
        sAt[tid] = (tb.z - tb.x) * (tb.w - tb.y) + EPSF;
    }
    __syncthreads();

    float acc[TT] = {0.f, 0.f, 0.f, 0.f, 0.f, 0.f, 0.f, 0.f};

    for (int bo = 0; bo < BZ; bo += 4) {
        float4 pb[4];
#pragma unroll
        for (int u = 0; u < 4; ++u)
            pb[u] = pred[(bz * BZ + bo + u) * NP + p];
#pragma unroll
        for (int u = 0; u < 4; ++u) {
            const int b = bo + u;
            float ap = (pb[u].z - pb[u].x) * (pb[u].w - pb[u].y);
            const float* tb = &tgt[((bz * BZ + b) * NT + t0) * 4];  // uniform -> s_load
#pragma unroll
            for (int tt = 0; tt < TT; ++tt) {
                float tx1 = tb[4 * tt + 0], ty1 = tb[4 * tt + 1];
                float tx2 = tb[4 * tt + 2], ty2 = tb[4 * tt + 3];
                float ix1 = fmaxf(pb[u].x, tx1);
                float iy1 = fmaxf(pb[u].y, ty1);
                float ix2 = fminf(pb[u].z, tx2);
                float iy2 = fminf(pb[u].w, ty2);
                float dx = fmaxf(ix2 - ix1, 0.f);
                float dy = fmaxf(iy2 - iy1, 0.f);
                float inter = dx * dy;
                float uni = (ap + sAt[b * TT + tt]) - inter;
                acc[tt] += inter * __builtin_amdgcn_rcpf(uni);
            }
        }
    }
#pragma unroll
    for (int tt = 0; tt < TT; ++tt)
        partial[((size_t)(bz * NT) + t0 + tt) * NP + p] = acc[tt];
}

__device__ inline u64 wave_min_u64(u64 k) {
#pragma unroll
    for (int off = 1; off < 64; off <<= 1) {
        u32 lo = (u32)__shfl_xor((int)(u32)k, off);
        u32 hi = (u32)__shfl_xor((int)(u32)(k >> 32), off);
        u64 o = ((u64)hi << 32) | lo;
        if (o < k) k = o;
    }
    return k;  // uniform across lanes
}

// ---------- phase 2: one wave: z-reduce row r, write cost row, top-8 ----------
__device__ inline void phase2_row(const float* __restrict__ partial,
                                  float* __restrict__ cost,
                                  u64* __restrict__ toplist,
                                  int r, int lane) {
    float* crow = cost + (size_t)r * NP;
    float v[32];
#pragma unroll
    for (int k = 0; k < 8; ++k) {
        const int off = k * 256 + 4 * lane;
        float4 s = {0.f, 0.f, 0.f, 0.f};
#pragma unroll
        for (int z = 0; z < NZ; ++z) {
            float4 a = *(const float4*)(partial + ((size_t)(z * NT) + r) * NP + off);
            s.x += a.x; s.y += a.y; s.z += a.z; s.w += a.w;
        }
        float4 c;
        c.x = 1.f - s.x * (1.f / NB);
        c.y = 1.f - s.y * (1.f / NB);
        c.z = 1.f - s.z * (1.f / NB);
        c.w = 1.f - s.w * (1.f / NB);
        *(float4*)(crow + off) = c;   // greedy fallback reads this
        v[4 * k + 0] = c.x; v[4 * k + 1] = c.y;
        v[4 * k + 2] = c.z; v[4 * k + 3] = c.w;
    }
    const u32 base = 4u * (u32)lane;
    u32 used = 0;
    for (int e = 0; e < TK; ++e) {
        u64 best = ~0ull;
        u32 bs = 0;
#pragma unroll
        for (int s = 0; s < 32; ++s) {
            u32 hb = ((used >> s) & 1u) ? 0xFFFFFFFFu : __float_as_uint(v[s]);
            u32 gidx = (u32)((s >> 2) * 256) + base + (u32)(s & 3);
            u64 key = ((u64)hb << 32) | gidx;
            if (key < best) { best = key; bs = (u32)s; }
        }
        u64 g = wave_min_u64(best);
        if (best == g) used |= (1u << bs);   // unique winner (idx in key)
        if (lane == 0) toplist[r * TK + e] = g;
    }
}

// cold path: exact masked argmin over the full cost row (first-occurrence)
__device__ void fallback_pick(const float* __restrict__ row, u32 m, int lane,
                              u32* pickIdx, float* pickVal) {
    u64 best = ~0ull;
#pragma unroll 1
    for (int k = 0; k < 8; ++k) {
        float4 q = *(const float4*)(row + k * 256 + 4 * lane);
        float vv[4] = {q.x, q.y, q.z, q.w};
#pragma unroll
        for (int e = 0; e < 4; ++e) {
            u32 gidx = (u32)(k * 256 + 4 * lane + e);
            int w = __builtin_amdgcn_ds_bpermute((int)((gidx >> 5) << 2), (int)m);
            bool taken = (((u32)w >> (gidx & 31)) & 1u) != 0u;
            u32 hb = taken ? 0xFFFFFFFFu : __float_as_uint(vv[e]);
            u64 key = ((u64)hb << 32) | gidx;
            if (key < best) best = key;
        }
    }
    best = wave_min_u64(best);
    *pickIdx = (u32)best & (NP - 1);
    *pickVal = __uint_as_float((u32)(best >> 32));
}

// ---------- phase 3: serial greedy, one wave, register-resident ----------
__device__ inline void phase3_greedy(const u64* __restrict__ toplist,
                                     const float* __restrict__ cost,
                                     float* __restrict__ out, int lane) {
    u32 idxr[32], vbr[32];
#pragma unroll
    for (int k = 0; k < 32; ++k) {
        u64 v = toplist[64 * k + lane];
        idxr[k] = (u32)v & (NP - 1);
        vbr[k] = (u32)(v >> 32);
    }

    u32 m = 0;
    float sum = 0.f;
    u64 A = ~0ull;

#pragma unroll
    for (int k = 0; k < 32; ++k) {
        const u32 idx = idxr[k];
        const u32 vb = vbr[k];
        int wn = 0;
        if (k < 31)
            wn = __builtin_amdgcn_ds_bpermute((int)((idxr[k + 1] >> 5) << 2), (int)m);

        u32 pk[RB];
#pragma unroll
        for (int gg = 0; gg < RB; ++gg) {
            u64 bal = A & (0xFFull << (8 * gg));
            u32 pickIdx; float pickVal;
            if (bal != 0) {                          // uniform branch
                int f = (int)__ffsll(bal) - 1;       // lowest lane = lowest rank
                pickIdx = (u32)__builtin_amdgcn_readlane((int)idx, f);
                pickVal = __uint_as_float((u32)__builtin_amdgcn_readlane((int)vb, f));
            } else {
                fallback_pick(cost + (size_t)(k * RB + gg) * NP, m, lane,
                              &pickIdx, &pickVal);
            }
            pk[gg] = pickIdx;
            sum += pickVal;
            if ((pickIdx >> 5) == (u32)lane) m |= (1u << (pickIdx & 31));
            A &= ~__ballot(idx == pickIdx);          // clear pick + in-batch dups
        }

        if (k < 31) {
            const u32 idn = idxr[k + 1];
            u64 An = __ballot((((u32)wn >> (idn & 31)) & 1u) == 0u);
#pragma unroll
            for (int gg = 0; gg < RB; ++gg)
                An &= ~__ballot(idn == pk[gg]);
            A = An;
        }
    }
    if (lane == 0) out[0] = sum * (1.f / NT);
}

// ---------- fused kernel: last-arriver promotion, NO cooperative API ----------
// done1[by] counts the 32 producer blocks (8 bx * 4 z) of target-group by; the
// block completing its group runs phase 2 for that group's 8 rows (overlapped
// with other groups' phase 1). done2 counts groups; the last runs phase 3.
// No spinning anywhere -> deadlock-free regardless of scheduling.
__global__ __launch_bounds__(256) void fused_kernel(const float4* __restrict__ pred,
                                                    const float* __restrict__ tgt,
                                                    float* __restrict__ partial,
                                                    float* __restrict__ cost,
                                                    u64* __restrict__ toplist,
                                                    u32* __restrict__ done1,
                                                    u32* __restrict__ done2,
                                                    float* __restrict__ out) {
    __shared__ float sAt[BZ * TT];
    __shared__ int sRole, sLast;
    const int tid = threadIdx.x;
    const int by = blockIdx.y;

    phase1(pred, tgt, partial, blockIdx.x, by, blockIdx.z, tid, sAt);

    __syncthreads();                       // all stores of this block issued+drained
    if (tid == 0) {
        __threadfence();                   // release partial writes
        sRole = (atomicAdd(&done1[by], 1u) == NZ * (NP / 256) - 1);
    }
    __syncthreads();

    if (sRole) {                           // block-uniform branch
        __threadfence();                   // acquire group's partials
        const int wave = tid >> 6, lane = tid & 63;
        phase2_row(partial, cost, toplist, by * TT + 2 * wave + 0, lane);
        phase2_row(partial, cost, toplist, by * TT + 2 * wave + 1, lane);
        __syncthreads();
        if (tid == 0) {
            __threadfence();               // release cost/toplist writes
            sLast = (atomicAdd(done2, 1u) == NT / TT - 1);
        }
        __syncthreads();
        if (sLast && tid < 64) {
            __threadfence();               // acquire all groups' cost/toplist
            phase3_greedy(toplist, cost, out, tid);
        }
    }
}

extern "C" void kernel_launch(void* const* d_in, const int* in_sizes, int n_in,
                              void* d_out, int out_size, void* d_ws, size_t ws_size,
                              hipStream_t stream) {
    const float4* pred = (const float4*)d_in[0];
    const float* tgt = (const float*)d_in[1];
    char* ws = (char*)d_ws;
    float* cost    = (float*)ws;                                   // 2 MB
    float* partial = (float*)(ws + (size_t)NT * NP * 4);           // 8 MB
    u64* toplist   = (u64*)(ws + (size_t)NT * NP * 4 * (1 + NZ));  // 16 KB
    u32* counters  = (u32*)(ws + (size_t)NT * NP * 4 * (1 + NZ) + (size_t)NT * TK * 8);
    u32* done1 = counters;          // [32]
    u32* done2 = counters + 32;     // [1]
    float* outp = (float*)d_out;

    hipMemsetAsync(counters, 0, 33 * sizeof(u32), stream);
    fused_kernel<<<dim3(NP / 256, NT / TT, NZ), 256, 0, stream>>>(
        pred, tgt, partial, cost, toplist, done1, done2, outp);
}

// Round 11
// 59.791 us; speedup vs baseline: 2.2522x; 2.2522x over previous
//
#include <hip/hip_runtime.h>
#include <hip/hip_bf16.h>

typedef unsigned long long u64;
typedef unsigned int u32;

#define NB 64
#define NP 2048
#define NT 256
#define TK 8          // sorted top-K kept per row
#define RB 8          // rows resolved per greedy batch (RB*TK = 64 lanes)
#define TT 4          // targets per cost block
#define PB 64         // preds per cost block (one wave)
#define EPSF 1e-7f

// K1: cost[t][p] = 1 - mean_b iou(pred[b][p], tgt[b][t]).
// Grid (32,64) = 2048 single-wave blocks (8/CU, no barriers in hot loop).
// Targets (coords + area+eps) fully in LDS: zero in-loop scalar loads.
__global__ __launch_bounds__(64) void cost_kernel(const float4* __restrict__ pred,
                                                  const float* __restrict__ tgt,
                                                  float* __restrict__ cost) {
    __shared__ float4 sT[NB * TT];   // [b][tt] coords
    __shared__ float  sA[NB * TT];   // area_t + eps
    const int lane = threadIdx.x;
    const int p = blockIdx.x * PB + lane;
    const int t0 = blockIdx.y * TT;

#pragma unroll
    for (int i = lane; i < NB * TT; i += 64) {
        int b = i >> 2, tt = i & 3;
        float4 tb = *(const float4*)&tgt[(b * NT + t0 + tt) * 4];
        sT[i] = tb;
        sA[i] = (tb.z - tb.x) * (tb.w - tb.y) + EPSF;
    }
    __syncthreads();   // one wave: compiles to a cheap lgkmcnt drain + barrier

    float acc[TT] = {0.f, 0.f, 0.f, 0.f};

    for (int b = 0; b < NB; b += 4) {
        float4 pb[4];
#pragma unroll
        for (int u = 0; u < 4; ++u) pb[u] = pred[(b + u) * NP + p];
#pragma unroll
        for (int u = 0; u < 4; ++u) {
            float ap = (pb[u].z - pb[u].x) * (pb[u].w - pb[u].y);
#pragma unroll
            for (int tt = 0; tt < TT; ++tt) {
                float4 tb = sT[(b + u) * TT + tt];   // broadcast ds_read_b128
                float at = sA[(b + u) * TT + tt];    // broadcast ds_read_b32
                float ix1 = fmaxf(pb[u].x, tb.x);
                float iy1 = fmaxf(pb[u].y, tb.y);
                float ix2 = fminf(pb[u].z, tb.z);
                float iy2 = fminf(pb[u].w, tb.w);
                float dx = fmaxf(ix2 - ix1, 0.f);
                float dy = fmaxf(iy2 - iy1, 0.f);
                float inter = dx * dy;
                float uni = (ap + at) - inter;
                acc[tt] += inter * __builtin_amdgcn_rcpf(uni);
            }
        }
    }
#pragma unroll
    for (int tt = 0; tt < TT; ++tt)
        cost[(size_t)(t0 + tt) * NP + p] = 1.f - acc[tt] * (1.f / NB);
}

__device__ inline u64 wave_min_u64(u64 k) {
#pragma unroll
    for (int off = 1; off < 64; off <<= 1) {
        u32 lo = (u32)__shfl_xor((int)(u32)k, off);
        u32 hi = (u32)__shfl_xor((int)(u32)(k >> 32), off);
        u64 o = ((u64)hi << 32) | lo;
        if (o < k) k = o;
    }
    return k;  // uniform across lanes
}

// K2: 4 waves/row. Each wave extracts sorted top-8 of its 512-element quarter
// on packed (valbits<<32 | idx) keys (argmin first-occurrence preserved);
// wave 0 merges the 32 candidates (top-8 of row is a subset of the union).
__global__ __launch_bounds__(256) void topk_kernel(const float* __restrict__ cost,
                                                   u64* __restrict__ toplist) {
    __shared__ u64 sK[32];
    const int tid = threadIdx.x;
    const int wv = tid >> 6, lane = tid & 63;
    const int t = blockIdx.x;
    const float* row = cost + (size_t)t * NP;

    float v[8];
#pragma unroll
    for (int c = 0; c < 2; ++c) {
        float4 q = *(const float4*)(row + wv * 512 + c * 256 + 4 * lane);
        v[4 * c + 0] = q.x; v[4 * c + 1] = q.y;
        v[4 * c + 2] = q.z; v[4 * c + 3] = q.w;
    }
    u32 used = 0;
    for (int e = 0; e < TK; ++e) {
        u64 best = ~0ull;
        u32 bs = 0;
#pragma unroll
        for (int s = 0; s < 8; ++s) {
            u32 hb = ((used >> s) & 1u) ? 0xFFFFFFFFu : __float_as_uint(v[s]);
            u32 gidx = (u32)(wv * 512 + (s >> 2) * 256 + 4 * lane + (s & 3));
            u64 key = ((u64)hb << 32) | gidx;
            if (key < best) { best = key; bs = (u32)s; }
        }
        u64 g = wave_min_u64(best);
        if (best == g) used |= (1u << bs);   // unique winner (idx in key)
        if (lane == 0) sK[wv * TK + e] = g;
    }
    __syncthreads();
    if (wv == 0) {
        u64 k = (lane < 32) ? sK[lane] : ~0ull;
        for (int e = 0; e < TK; ++e) {
            u64 g = wave_min_u64(k);
            if (k == g) k = ~0ull;           // clear unique winner
            if (lane == 0) toplist[t * TK + e] = g;
        }
    }
}

// cold path: exact masked argmin over the full cost row (first-occurrence)
__device__ void fallback_pick(const float* __restrict__ row, u32 m, int lane,
                              u32* pickIdx, float* pickVal) {
    u64 best = ~0ull;
#pragma unroll 1
    for (int k = 0; k < 8; ++k) {
        float4 q = *(const float4*)(row + k * 256 + 4 * lane);
        float vv[4] = {q.x, q.y, q.z, q.w};
#pragma unroll
        for (int e = 0; e < 4; ++e) {
            u32 gidx = (u32)(k * 256 + 4 * lane + e);
            int w = __builtin_amdgcn_ds_bpermute((int)((gidx >> 5) << 2), (int)m);
            bool taken = (((u32)w >> (gidx & 31)) & 1u) != 0u;
            u32 hb = taken ? 0xFFFFFFFFu : __float_as_uint(vv[e]);
            u64 key = ((u64)hb << 32) | gidx;
            if (key < best) best = key;
        }
    }
    best = wave_min_u64(best);
    *pickIdx = (u32)best & (NP - 1);
    *pickVal = __uint_as_float((u32)(best >> 32));
}

// K3: serial greedy, one wave, toplist fully register-resident (validated).
__global__ __launch_bounds__(64) void greedy_kernel(const u64* __restrict__ toplist,
                                                    const float* __restrict__ cost,
                                                    float* __restrict__ out) {
    const int lane = threadIdx.x;
    u32 idxr[32], vbr[32];
#pragma unroll
    for (int k = 0; k < 32; ++k) {
        u64 v = toplist[64 * k + lane];
        idxr[k] = (u32)v & (NP - 1);
        vbr[k] = (u32)(v >> 32);
    }

    u32 m = 0;
    float sum = 0.f;
    u64 A = ~0ull;

#pragma unroll
    for (int k = 0; k < 32; ++k) {
        const u32 idx = idxr[k];
        const u32 vb = vbr[k];
        int wn = 0;
        if (k < 31)
            wn = __builtin_amdgcn_ds_bpermute((int)((idxr[k + 1] >> 5) << 2), (int)m);

        u32 pk[RB];
#pragma unroll
        for (int gg = 0; gg < RB; ++gg) {
            u64 bal = A & (0xFFull << (8 * gg));
            u32 pickIdx; float pickVal;
            if (bal != 0) {                          // uniform branch
                int f = (int)__ffsll(bal) - 1;       // lowest lane = lowest rank
                pickIdx = (u32)__builtin_amdgcn_readlane((int)idx, f);
                pickVal = __uint_as_float((u32)__builtin_amdgcn_readlane((int)vb, f));
            } else {
                fallback_pick(cost + (size_t)(k * RB + gg) * NP, m, lane,
                              &pickIdx, &pickVal);
            }
            pk[gg] = pickIdx;
            sum += pickVal;
            if ((pickIdx >> 5) == (u32)lane) m |= (1u << (pickIdx & 31));
            A &= ~__ballot(idx == pickIdx);          // clear pick + in-batch dups
        }

        if (k < 31) {
            const u32 idn = idxr[k + 1];
            u64 An = __ballot((((u32)wn >> (idn & 31)) & 1u) == 0u);
#pragma unroll
            for (int gg = 0; gg < RB; ++gg)
                An &= ~__ballot(idn == pk[gg]);
            A = An;
        }
    }
    if (lane == 0) out[0] = sum * (1.f / NT);
}

extern "C" void kernel_launch(void* const* d_in, const int* in_sizes, int n_in,
                              void* d_out, int out_size, void* d_ws, size_t ws_size,
                              hipStream_t stream) {
    const float4* pred = (const float4*)d_in[0];
    const float* tgt = (const float*)d_in[1];
    char* ws = (char*)d_ws;
    float* cost  = (float*)ws;                           // 2 MB
    u64* toplist = (u64*)(ws + (size_t)NT * NP * 4);     // 16 KB

    cost_kernel<<<dim3(NP / PB, NT / TT), PB, 0, stream>>>(pred, tgt, cost);
    topk_kernel<<<NT, 256, 0, stream>>>(cost, toplist);
    greedy_kernel<<<1, 64, 0, stream>>>(toplist, cost, (float*)d_out);
}